// Round 1
// 628.319 us; speedup vs baseline: 1.3600x; 1.3600x over previous
//
#include <hip/hip_runtime.h>
#include <math.h>

#define Bc 32
#define Lc 512
#define Hc 8
#define Ec 64
#define Sc 512

typedef __attribute__((ext_vector_type(8))) short short8;
typedef __attribute__((ext_vector_type(4))) float f32x4;

// ---------- helpers ----------
__device__ inline unsigned short f2bf(float x) {           // fp32 -> bf16 RNE
    unsigned u = __float_as_uint(x);
    return (unsigned short)((u + 0x7fffu + ((u >> 16) & 1u)) >> 16);
}
__device__ inline float bf2f(unsigned short s) {
    return __uint_as_float(((unsigned)s) << 16);
}

// ---------- pack kernels ----------
// K fp32 [b][s][h][e] -> planar bf16 hi/lo [b][h][s][e]
// (planar so attn loads short8 fragments directly: no in-loop unpack VALU)
__global__ __launch_bounds__(256) void pack_k(const float* __restrict__ src,
                                              unsigned short* __restrict__ hi,
                                              unsigned short* __restrict__ lo) {
    const int t = threadIdx.x;
    const int b = blockIdx.z, h = blockIdx.y, s0 = blockIdx.x * 32;
    const int e4 = (t & 15) * 4;
    const int sr = t >> 4;                       // 0..15
    #pragma unroll
    for (int i = 0; i < 2; ++i) {
        const int s = s0 + sr + 16 * i;
        const float4 v = *(const float4*)&src[(((size_t)b * Lc + s) * Hc + h) * Ec + e4];
        ushort4 vh, vl;
        vh.x = f2bf(v.x); vl.x = f2bf(v.x - bf2f(vh.x));
        vh.y = f2bf(v.y); vl.y = f2bf(v.y - bf2f(vh.y));
        vh.z = f2bf(v.z); vl.z = f2bf(v.z - bf2f(vh.z));
        vh.w = f2bf(v.w); vl.w = f2bf(v.w - bf2f(vh.w));
        const size_t o = (((size_t)b * Hc + h) * Lc + s) * Ec + e4;
        *(ushort4*)&hi[o] = vh;
        *(ushort4*)&lo[o] = vl;
    }
}

// V fp32 [b][s][h][e] -> bf16 V^T [b][h][e][s]
__global__ __launch_bounds__(256) void pack_vt(const float* __restrict__ V,
                                               unsigned short* __restrict__ Vt) {
    __shared__ float LT[64 * 68];
    const int t = threadIdx.x;
    const int b = blockIdx.z, h = blockIdx.y, s0 = blockIdx.x * 64;
    #pragma unroll
    for (int i = 0; i < 16; ++i) {
        const int idx = t + 256 * i;
        const int e = idx & 63, s = idx >> 6;
        LT[e * 68 + s] = V[(((size_t)b * Lc + s0 + s) * Hc + h) * Ec + e];
    }
    __syncthreads();
    #pragma unroll
    for (int i = 0; i < 16; ++i) {
        const int idx = t + 256 * i;
        const int s = idx & 63, e = idx >> 6;
        Vt[((size_t)(b * Hc + h) * Ec + e) * Sc + s0 + s] = f2bf(LT[e * 68 + s]);
    }
}

// ---------- prior ----------
__global__ __launch_bounds__(256) void prior_kernel(
    const float* __restrict__ sigma, float* __restrict__ prior)
{
    const int wave = threadIdx.x >> 6;
    const int lane = threadIdx.x & 63;
    const int row  = blockIdx.x * 4 + wave;      // (b*H+h)*L + l
    const int l    = row & (Lc - 1);
    const int bh   = row >> 9;
    const int b    = bh >> 3;
    const int h    = bh & (Hc - 1);

    float sg = sigma[((size_t)b * Lc + l) * Hc + h];
    sg = 1.0f / (1.0f + __expf(-5.0f * sg)) + 1e-5f;
    sg = expm1f(sg * 1.0986122886681098f);
    const float inv = 0.3989422804014327f / sg;
    const float c2  = -0.5f / (sg * sg);

    const size_t base = (size_t)row * Sc;
    #pragma unroll
    for (int i = 0; i < 2; ++i) {
        const int s0 = i * 256 + lane * 4;
        const float d0 = (float)(l - (s0 + 0));
        const float d1 = (float)(l - (s0 + 1));
        const float d2 = (float)(l - (s0 + 2));
        const float d3 = (float)(l - (s0 + 3));
        float4 o;
        o.x = inv * __expf(c2 * d0 * d0);
        o.y = inv * __expf(c2 * d1 * d1);
        o.z = inv * __expf(c2 * d2 * d2);
        o.w = inv * __expf(c2 * d3 * d3);
        *(float4*)&prior[base + s0] = o;
    }
}

// ---------- fused attention (swapped MFMA, LDS-free, barrier-free) ----------
// Computes S^T = K·Q^T with a sigma-permuted A-row order so that each lane's
// accumulator registers are ALREADY the PV B-fragment (P^T) layout:
//   acc[nt][r] = P^T[s][l16],  s = (nt>>1)*32 + quad*8 + (nt&1)*4 + r
// Softmax over s for fixed l is 128 in-lane values + shfl_xor(16/32) across quads.
// PV: O^T = V^T · P^T  with A = V^T fragments read straight from global (L2-hot).
// 256 thr = 4 independent waves, each owning 16 query rows. No LDS, no barriers.
__global__ __launch_bounds__(256, 2) void attn_mfma(
    const float* __restrict__ Q, const unsigned short* __restrict__ Khi,
    const unsigned short* __restrict__ Klo, const unsigned short* __restrict__ Vt,
    float* __restrict__ outV, float* __restrict__ series)
{
    const int t    = threadIdx.x;
    const int lane = t & 63, wave = t >> 6;
    const int quad = lane >> 4, l16 = lane & 15;

    // XCD swizzle: the 8 l-tile blocks of one (b,h) share one XCD's L2
    // (K planes 128KB + V^T 64KB stay resident). bid -> (xcd, xt, bh_hi) bijective.
    const int bid = blockIdx.x;                  // 0..2047
    const int xcd = bid & 7;
    const int rr  = bid >> 3;
    const int xt  = rr & 7;                      // l-tile group 0..7
    const int bh  = (rr >> 3) * 8 + xcd;         // 0..255
    const int b = bh >> 3, h = bh & 7;
    const int l = xt * 64 + wave * 16 + l16;     // this lane's query row

    const size_t kb = (size_t)bh * Lc * Ec;

    // ---- Q B-frags (hi/lo split), one-time fp32 -> bf16 convert ----
    short8 qh[2], ql[2];
    {
        const float* qp = &Q[(((size_t)b * Lc + l) * Hc + h) * Ec + quad * 8];
        #pragma unroll
        for (int kt = 0; kt < 2; ++kt) {
            const float4 v0 = *(const float4*)(qp + kt * 32);
            const float4 v1 = *(const float4*)(qp + kt * 32 + 4);
            const float vv[8] = {v0.x, v0.y, v0.z, v0.w, v1.x, v1.y, v1.z, v1.w};
            #pragma unroll
            for (int j = 0; j < 8; ++j) {
                const unsigned short hb = f2bf(vv[j]);
                qh[kt][j] = (short)hb;
                ql[kt][j] = (short)f2bf(vv[j] - bf2f(hb));
            }
        }
    }

    // ---- QK^T (transposed, 3-term split bf16) ----
    f32x4 acc[32];
    #pragma unroll
    for (int nt = 0; nt < 32; ++nt) { acc[nt][0]=0.f; acc[nt][1]=0.f; acc[nt][2]=0.f; acc[nt][3]=0.f; }

    // A-frag row permutation: frag row m -> s offset sigma_p(m) = (m>>2)*8 + p*4 + (m&3)
    const int arow = (l16 >> 2) * 8 + (l16 & 3);
    #pragma unroll
    for (int nt = 0; nt < 32; ++nt) {
        const int s = (nt >> 1) * 32 + arow + (nt & 1) * 4;
        const unsigned short* kp = &Khi[kb + (size_t)s * Ec + quad * 8];
        const unsigned short* lp = &Klo[kb + (size_t)s * Ec + quad * 8];
        #pragma unroll
        for (int kt = 0; kt < 2; ++kt) {
            const short8 kh = *(const short8*)(kp + kt * 32);
            const short8 kl = *(const short8*)(lp + kt * 32);
            acc[nt] = __builtin_amdgcn_mfma_f32_16x16x32_bf16(kh, qh[kt], acc[nt], 0, 0, 0);
            acc[nt] = __builtin_amdgcn_mfma_f32_16x16x32_bf16(kl, qh[kt], acc[nt], 0, 0, 0);
            acc[nt] = __builtin_amdgcn_mfma_f32_16x16x32_bf16(kh, ql[kt], acc[nt], 0, 0, 0);
        }
    }

    // ---- softmax over s for this lane's l: 128 in-lane + butterfly over quads ----
    float mx = acc[0][0];
    #pragma unroll
    for (int nt = 0; nt < 32; ++nt) {
        #pragma unroll
        for (int r4 = 0; r4 < 4; ++r4) mx = fmaxf(mx, acc[nt][r4]);
    }
    mx = fmaxf(mx, __shfl_xor(mx, 16));
    mx = fmaxf(mx, __shfl_xor(mx, 32));
    float ssum = 0.f;
    #pragma unroll
    for (int nt = 0; nt < 32; ++nt) {
        #pragma unroll
        for (int r4 = 0; r4 < 4; ++r4) {
            const float e = __expf((acc[nt][r4] - mx) * 0.125f);   // scale = 1/sqrt(64)
            acc[nt][r4] = e; ssum += e;
        }
    }
    ssum += __shfl_xor(ssum, 16);
    ssum += __shfl_xor(ssum, 32);
    const float is = 1.f / ssum;
    #pragma unroll
    for (int nt = 0; nt < 32; ++nt) {
        acc[nt][0] *= is; acc[nt][1] *= is; acc[nt][2] *= is; acc[nt][3] *= is;
    }

    // ---- fused: series store (exact fp32) + PV (O^T = V^T . P^T) ----
    f32x4 oaccT[4];
    #pragma unroll
    for (int et = 0; et < 4; ++et) { oaccT[et][0]=0.f; oaccT[et][1]=0.f; oaccT[et][2]=0.f; oaccT[et][3]=0.f; }

    const unsigned short* vb = &Vt[(size_t)bh * Ec * Sc];
    float* srow = &series[((size_t)bh * Lc + l) * Sc];
    #pragma unroll
    for (int t2 = 0; t2 < 16; ++t2) {
        const f32x4 p0 = acc[2 * t2];          // s = t2*32 + quad*8 + {0..3}
        const f32x4 p1 = acc[2 * t2 + 1];      // s = t2*32 + quad*8 + {4..7}
        *(f32x4*)&srow[t2 * 32 + quad * 8]     = p0;
        *(f32x4*)&srow[t2 * 32 + quad * 8 + 4] = p1;
        short8 pb;                              // B-frag P^T, straight from registers
        pb[0] = (short)f2bf(p0[0]); pb[1] = (short)f2bf(p0[1]);
        pb[2] = (short)f2bf(p0[2]); pb[3] = (short)f2bf(p0[3]);
        pb[4] = (short)f2bf(p1[0]); pb[5] = (short)f2bf(p1[1]);
        pb[6] = (short)f2bf(p1[2]); pb[7] = (short)f2bf(p1[3]);
        #pragma unroll
        for (int et = 0; et < 4; ++et) {
            const short8 vf = *(const short8*)&vb[(size_t)(et * 16 + l16) * Sc + t2 * 32 + quad * 8];
            oaccT[et] = __builtin_amdgcn_mfma_f32_16x16x32_bf16(vf, pb, oaccT[et], 0, 0, 0);
        }
    }

    // ---- epilogue: oaccT[et][r] = O^T[e = et*16+quad*4+r][l] -> float4 stores ----
    #pragma unroll
    for (int et = 0; et < 4; ++et) {
        float4 o;
        o.x = oaccT[et][0]; o.y = oaccT[et][1]; o.z = oaccT[et][2]; o.w = oaccT[et][3];
        *(float4*)&outV[(((size_t)b * Lc + l) * Hc + h) * Ec + et * 16 + quad * 4] = o;
    }
}

extern "C" void kernel_launch(void* const* d_in, const int* in_sizes, int n_in,
                              void* d_out, int out_size, void* d_ws, size_t ws_size,
                              hipStream_t stream) {
    (void)d_ws; (void)ws_size; (void)n_in; (void)in_sizes; (void)out_size;
    const float* Q  = (const float*)d_in[0];
    const float* K  = (const float*)d_in[1];
    const float* Vv = (const float*)d_in[2];
    const float* sg = (const float*)d_in[3];

    float* outV   = (float*)d_out;                               // [B,L,H,E]
    float* series = outV + (size_t)Bc * Lc * Hc * Ec;            // [B,H,L,S]
    float* prior  = series + (size_t)Bc * Hc * Lc * Sc;          // [B,H,L,S]

    // Scratch (50 MB) lives inside the prior region (268 MB); prior_kernel
    // runs last and overwrites it.
    unsigned short* Khi = (unsigned short*)prior;
    unsigned short* Klo = Khi + (size_t)Bc * Hc * Lc * Ec;
    unsigned short* Vt  = Klo + (size_t)Bc * Hc * Lc * Ec;

    pack_k <<<dim3(Lc / 32, Hc, Bc), 256, 0, stream>>>(K, Khi, Klo);
    pack_vt<<<dim3(Lc / 64, Hc, Bc), 256, 0, stream>>>(Vv, Vt);
    attn_mfma<<<dim3((Bc * Hc * Lc) / 64 / 4, 1, 1), 256, 0, stream>>>(Q, Khi, Klo, Vt, outV, series);
    prior_kernel<<<(Bc * Hc * Lc) / 4, 256, 0, stream>>>(sg, prior);
}